// Round 6
// baseline (2321.167 us; speedup 1.0000x reference)
//
#include <hip/hip_runtime.h>

typedef float    f32x4  __attribute__((ext_vector_type(4)));
typedef __bf16   bf16x8 __attribute__((ext_vector_type(8)));
typedef unsigned short u16;

#define DK      1536
#define KSTEPS  48      // 1536 / 32
#define BM      128
#define BN      128
#define NQ      6272    // 32*196
#define NM      65536
#define NG      32      // grid.x groups of n-tiles
#define NTPER   16      // 512 n-tiles / NG

__device__ __forceinline__ u16 f2bf(float f) {
    unsigned x = __float_as_uint(f);
    return (u16)((x + 0x7fffu + ((x >> 16) & 1u)) >> 16);  // RNE
}

__device__ __forceinline__ void gload16(const void* g, void* l) {
    __builtin_amdgcn_global_load_lds(
        (__attribute__((address_space(1))) unsigned int*)(void*)g,
        (__attribute__((address_space(3))) unsigned int*)l,
        16, 0, 0);
}

// One wave per row: L2-normalize f32 row -> bf16 row.
__global__ void __launch_bounds__(256) norm_rows_kernel(const float* __restrict__ in,
                                                        u16* __restrict__ out, int nrows) {
    int gw = (int)((blockIdx.x * 256u + threadIdx.x) >> 6);
    int l  = threadIdx.x & 63;
    if (gw >= nrows) return;
    const float4* rp = (const float4*)(in + (size_t)gw * DK);
    float4 v[6];
    float s = 0.f;
#pragma unroll
    for (int i = 0; i < 6; ++i) {
        v[i] = rp[i * 64 + l];
        s += v[i].x * v[i].x + v[i].y * v[i].y + v[i].z * v[i].z + v[i].w * v[i].w;
    }
#pragma unroll
    for (int m = 1; m < 64; m <<= 1) s += __shfl_xor(s, m, 64);
    float inv = 1.0f / fmaxf(sqrtf(s), 1e-12f);
    ushort4* op = (ushort4*)(out + (size_t)gw * DK);
#pragma unroll
    for (int i = 0; i < 6; ++i) {
        ushort4 u;
        u.x = f2bf(v[i].x * inv); u.y = f2bf(v[i].y * inv);
        u.z = f2bf(v[i].z * inv); u.w = f2bf(v[i].w * inv);
        op[i * 64 + l] = u;
    }
}

// Fused GEMM + per-row max-dot -> atomicMin of d^2 (uint-ordered, d^2 >= 0).
// Block: 256 thr (4 waves, 2x2), tile 128q x 128n, BK=32, loops NTPER n-tiles.
__global__ void __launch_bounds__(256, 2)
gemm_min_kernel(const u16* __restrict__ Qn, const u16* __restrict__ Bn,
                unsigned* __restrict__ best) {
    __shared__ char smem[16384];  // A: [0,8192) B: [8192,16384), each 128 rows x 64 B
    const int tid = threadIdx.x;
    const int l   = tid & 63;
    const int w   = tid >> 6;
    const int wr  = w >> 1, wc = w & 1;
    const int kb  = l >> 4, mn = l & 15;
    const int q0  = blockIdx.y * BM;

    // staging: thread t fills LDS physical bytes [t*16, t*16+16) per 4096B round.
    // physical row = t>>2 (+64/round), swizzle: logical colbyte = pcol ^ ((row&3)<<4)
    const int srow  = tid >> 2;
    const int lcolb = ((tid & 3) << 4) ^ ((srow & 3) << 4);
    const u16* gA0 = Qn + (size_t)(q0 + srow) * DK + (lcolb >> 1);
    const u16* gA1 = gA0 + (size_t)64 * DK;
    char* ldsA = smem + w * 1024;          // wave-uniform dest base
    char* ldsB = smem + 8192 + w * 1024;

    float rowmax[4][4];
#pragma unroll
    for (int i = 0; i < 4; ++i)
#pragma unroll
        for (int r = 0; r < 4; ++r) rowmax[i][r] = -3.0e38f;

    // fragment LDS byte offsets (swizzled read side), loop-invariant
    int aoff[4], boff[4];
#pragma unroll
    for (int i = 0; i < 4; ++i) {
        int arow = wr * 64 + i * 16 + mn;
        aoff[i] = arow * 64 + ((kb << 4) ^ ((arow & 3) << 4));
        int brow = wc * 64 + i * 16 + mn;
        boff[i] = 8192 + brow * 64 + ((kb << 4) ^ ((brow & 3) << 4));
    }

    for (int nt = 0; nt < NTPER; ++nt) {
        const int n0 = (blockIdx.x * NTPER + nt) * BN;
        const u16* gB0 = Bn + (size_t)(n0 + srow) * DK + (lcolb >> 1);
        const u16* gB1 = gB0 + (size_t)64 * DK;

        f32x4 acc[4][4];
#pragma unroll
        for (int i = 0; i < 4; ++i)
#pragma unroll
            for (int j = 0; j < 4; ++j)
#pragma unroll
                for (int c = 0; c < 4; ++c) acc[i][j][c] = 0.f;

        for (int kt = 0; kt < KSTEPS; ++kt) {
            const int ke = kt * 32;  // element (bf16) offset into the row
            gload16(gA0 + ke, ldsA);
            gload16(gA1 + ke, ldsA + 4096);
            gload16(gB0 + ke, ldsB);
            gload16(gB1 + ke, ldsB + 4096);
            __syncthreads();  // drains vmcnt -> staged tile visible
            bf16x8 a[4], b[4];
#pragma unroll
            for (int i = 0; i < 4; ++i) a[i] = *(const bf16x8*)(smem + aoff[i]);
#pragma unroll
            for (int j = 0; j < 4; ++j) b[j] = *(const bf16x8*)(smem + boff[j]);
#pragma unroll
            for (int i = 0; i < 4; ++i)
#pragma unroll
                for (int j = 0; j < 4; ++j)
                    acc[i][j] = __builtin_amdgcn_mfma_f32_16x16x32_bf16(a[i], b[j], acc[i][j], 0, 0, 0);
            __syncthreads();  // protect LDS before next stage
        }

        // per-row max over this n-tile: 4 col-frags then 16-lane group reduce
#pragma unroll
        for (int i = 0; i < 4; ++i)
#pragma unroll
            for (int r = 0; r < 4; ++r) {
                float v = fmaxf(fmaxf(acc[i][0][r], acc[i][1][r]),
                                fmaxf(acc[i][2][r], acc[i][3][r]));
                v = fmaxf(v, __shfl_xor(v, 1, 64));
                v = fmaxf(v, __shfl_xor(v, 2, 64));
                v = fmaxf(v, __shfl_xor(v, 4, 64));
                v = fmaxf(v, __shfl_xor(v, 8, 64));
                rowmax[i][r] = fmaxf(rowmax[i][r], v);
            }
    }

    if (mn == 0) {  // one lane per 16-group owns rows kb*4 + r
#pragma unroll
        for (int i = 0; i < 4; ++i)
#pragma unroll
            for (int r = 0; r < 4; ++r) {
                int row = q0 + wr * 64 + i * 16 + kb * 4 + r;
                float d2 = fmaxf(2.0f - 2.0f * rowmax[i][r], 0.0f);
                atomicMin(best + row, __float_as_uint(d2));
            }
    }
}

// One wave per batch: d = sqrt(d2), mean of top-20 of 196.
__global__ void topk_kernel(const unsigned* __restrict__ best, float* __restrict__ out) {
    const int b = blockIdx.x;
    const int l = threadIdx.x;  // 64 threads
    float v[4];
#pragma unroll
    for (int s = 0; s < 4; ++s) {
        int idx = s * 64 + l;
        v[s] = (idx < 196) ? sqrtf(__uint_as_float(best[b * 196 + idx])) : -1.0f;
    }
    float sum = 0.f;
    for (int it = 0; it < 20; ++it) {
        float m = v[0]; int slot = 0;
#pragma unroll
        for (int s = 1; s < 4; ++s) if (v[s] > m) { m = v[s]; slot = s; }
        float wm = m;
#pragma unroll
        for (int msk = 1; msk < 64; msk <<= 1) wm = fmaxf(wm, __shfl_xor(wm, msk, 64));
        sum += wm;
        unsigned long long owners = __ballot(m == wm);
        int first = __ffsll((unsigned long long)owners) - 1;
        if (l == first) v[slot] = -1.0f;
    }
    if (l == 0) out[b] = sum * (1.0f / 20.0f);
}

__global__ void fill_kernel(float* out, int n, float val) {
    int i = blockIdx.x * blockDim.x + threadIdx.x;
    if (i < n) out[i] = val;
}

extern "C" void kernel_launch(void* const* d_in, const int* in_sizes, int n_in,
                              void* d_out, int out_size, void* d_ws, size_t ws_size,
                              hipStream_t stream) {
    const float* patch = (const float*)d_in[0];
    const float* bank  = (const float*)d_in[1];
    float* out = (float*)d_out;

    const size_t bankBytes = (size_t)NM * DK * 2;      // 201.3 MB bf16
    const size_t qOff      = bankBytes;
    const size_t qBytes    = (size_t)NQ * DK * 2;      // 19.3 MB bf16
    const size_t bestOff   = qOff + qBytes;
    const size_t need      = bestOff + (size_t)NQ * 4;

    if (ws_size < need) {  // visible sentinel: ws too small
        fill_kernel<<<1, 64, 0, stream>>>(out, out_size, 1.0e9f);
        return;
    }

    u16*      bankB = (u16*)((char*)d_ws);
    u16*      qB    = (u16*)((char*)d_ws + qOff);
    unsigned* best  = (unsigned*)((char*)d_ws + bestOff);

    norm_rows_kernel<<<dim3(NM / 4), 256, 0, stream>>>(bank, bankB, NM);
    norm_rows_kernel<<<dim3(NQ / 4), 256, 0, stream>>>(patch, qB, NQ);
    hipMemsetAsync(best, 0x7F, (size_t)NQ * 4, stream);  // +big float, uint-ordered
    gemm_min_kernel<<<dim3(NG, NQ / BM), 256, 0, stream>>>(qB, bankB, best);
    topk_kernel<<<dim3(32), 64, 0, stream>>>(best, out);
}

// Round 9
// 1607.057 us; speedup vs baseline: 1.4444x; 1.4444x over previous
//
#include <hip/hip_runtime.h>

typedef float    f32x4  __attribute__((ext_vector_type(4)));
typedef __bf16   bf16x8 __attribute__((ext_vector_type(8)));
typedef unsigned short u16;

#define DK    1536
#define NQ    6272       // 32*196
#define NQP   6400       // padded to 25*256
#define NM    65536
#define NKT   24         // K-tiles per work: 1536/64
#define WPB   25         // works per block (256 blocks x 25 = 6400 = 25 mt x 256 nt)
#define TPB   (WPB*NKT)  // 600 K-tiles per block

__device__ __forceinline__ u16 f2bf(float f) {
    unsigned x = __float_as_uint(f);
    return (u16)((x + 0x7fffu + ((x >> 16) & 1u)) >> 16);  // RNE
}

__device__ __forceinline__ void gload16(const void* g, void* l) {
    __builtin_amdgcn_global_load_lds(
        (__attribute__((address_space(1))) unsigned int*)(void*)g,
        (__attribute__((address_space(3))) unsigned int*)l,
        16, 0, 0);
}

// One wave per row: L2-normalize f32 row -> bf16 row.
__global__ void __launch_bounds__(256) norm_rows_kernel(const float* __restrict__ in,
                                                        u16* __restrict__ out, int nrows) {
    int gw = (int)((blockIdx.x * 256u + threadIdx.x) >> 6);
    int l  = threadIdx.x & 63;
    if (gw >= nrows) return;
    const float4* rp = (const float4*)(in + (size_t)gw * DK);
    float4 v[6];
    float s = 0.f;
#pragma unroll
    for (int i = 0; i < 6; ++i) {
        v[i] = rp[i * 64 + l];
        s += v[i].x * v[i].x + v[i].y * v[i].y + v[i].z * v[i].z + v[i].w * v[i].w;
    }
#pragma unroll
    for (int m = 1; m < 64; m <<= 1) s += __shfl_xor(s, m, 64);
    float inv = 1.0f / fmaxf(sqrtf(s), 1e-12f);
    ushort4* op = (ushort4*)(out + (size_t)gw * DK);
#pragma unroll
    for (int i = 0; i < 6; ++i) {
        ushort4 u;
        u.x = f2bf(v[i].x * inv); u.y = f2bf(v[i].y * inv);
        u.z = f2bf(v[i].z * inv); u.w = f2bf(v[i].w * inv);
        op[i * 64 + l] = u;
    }
}

// 8-phase pipelined fused GEMM + per-row max-dot -> atomicMin of d^2.
// 256x256 tile, BK=64, 8 waves (2m x 4n), LDS ring of 8 x 16KB K-half units
// (Ak0,Bk0,Ak1,Bk1 per K-tile), stage-ahead 4 phases, counted vmcnt (never 0).
// Staging is UNCONDITIONAL (final tile stages a clamped dummy) so the vmcnt
// ledger stays in steady state through the last K-tile (race fix, r8).
// Per-wave C = 128x64 = acc[8][4] f32x4. Persistent: 256 blocks x 25 works.
__global__ __launch_bounds__(512, 2) void gemm8_kernel(const u16* __restrict__ Qn,
                                                       const u16* __restrict__ Bn,
                                                       unsigned* __restrict__ best) {
    extern __shared__ char smem[];
    const int tid = threadIdx.x;
    const int l   = tid & 63;
    const int w   = tid >> 6;
    const int wm  = w >> 2, wn = w & 3;
    const int kb  = l >> 4, mn = l & 15;

    // T1 bijective XCD swizzle (256 = 8 XCD x 32)
    const int bs = ((blockIdx.x & 7) << 5) | (blockIdx.x >> 3);
    const int W0 = bs * WPB;

    // staging thread constants: thread writes LDS phys (row=tid>>2 [+128], slot16=tid&3);
    // source column pre-swizzled (inverse == same XOR): logical16 = (tid&3)^((row>>1)&3)
    const int r0 = tid >> 2;
    const size_t soff0 = (size_t)r0 * DK + 8 * ((tid & 3) ^ ((r0 >> 1) & 3));
    const int r1 = r0 + 128;
    const size_t soff1 = (size_t)r1 * DK + 8 * ((tid & 3) ^ ((r1 >> 1) & 3));
    char* const ldst = smem + tid * 16;

    // read-side swizzled offsets within a 16KB unit (row stride 64B, 4x16B slots)
    int aoff[8], boff[4];
#pragma unroll
    for (int m = 0; m < 8; ++m) {
        int row = wm * 128 + m * 16 + mn;
        aoff[m] = row * 64 + 16 * (kb ^ ((row >> 1) & 3));
    }
#pragma unroll
    for (int n = 0; n < 4; ++n) {
        int row = wn * 64 + n * 16 + mn;
        boff[n] = row * 64 + 16 * (kb ^ ((row >> 1) & 3));
    }

    f32x4 acc[8][4];
#pragma unroll
    for (int m = 0; m < 8; ++m)
#pragma unroll
        for (int n = 0; n < 4; ++n)
#pragma unroll
            for (int c = 0; c < 4; ++c) acc[m][n][c] = 0.f;
    float rm[8][4];
#pragma unroll
    for (int m = 0; m < 8; ++m)
#pragma unroll
        for (int r = 0; r < 4; ++r) rm[m][r] = -3.0e38f;

    // staging stream state: decodes tile t+1
    int s_kt = 1, s_W = W0;
    const u16* sA = Qn + (size_t)(s_W >> 8) * 256 * DK;
    const u16* sB = Bn + (size_t)(s_W & 255) * 256 * DK;
    // compute stream state
    int c_kt = 0, c_W = W0;

    // prologue: stage tile 0 (kinds Ak0,Bk0,Ak1,Bk1 -> slots 0..3), col base kt=0
    gload16(sA + soff0, ldst + 0 * 16384); gload16(sA + soff1, ldst + 0 * 16384 + 8192);
    gload16(sB + soff0, ldst + 1 * 16384); gload16(sB + soff1, ldst + 1 * 16384 + 8192);
    gload16(sA + 32 + soff0, ldst + 2 * 16384); gload16(sA + 32 + soff1, ldst + 2 * 16384 + 8192);
    gload16(sB + 32 + soff0, ldst + 3 * 16384); gload16(sB + 32 + soff1, ldst + 3 * 16384 + 8192);
    asm volatile("s_waitcnt vmcnt(4)" ::: "memory");
    __builtin_amdgcn_s_barrier();

#pragma unroll 1
    for (int t = 0; t < TPB; ++t) {
        char* const Scur = smem + (((t & 1) << 2) * 16384);
        char* const ldsn = ldst + ((((t + 1) & 1) << 2) * 16384);
        const size_t scol = (size_t)(s_kt << 6);

        bf16x8 av[8], bv[2];

        // ---- phase 0: ks0, n{0,1}; stage Ak0(t+1)
#pragma unroll
        for (int m = 0; m < 8; ++m) av[m] = *(const bf16x8*)(Scur + 0 * 16384 + aoff[m]);
        bv[0] = *(const bf16x8*)(Scur + 1 * 16384 + boff[0]);
        bv[1] = *(const bf16x8*)(Scur + 1 * 16384 + boff[1]);
        gload16(sA + scol + soff0, ldsn + 0 * 16384);
        gload16(sA + scol + soff1, ldsn + 0 * 16384 + 8192);
        asm volatile("s_waitcnt vmcnt(6)" ::: "memory");
        __builtin_amdgcn_s_barrier();
        __builtin_amdgcn_s_setprio(1);
#pragma unroll
        for (int m = 0; m < 8; ++m) {
            acc[m][0] = __builtin_amdgcn_mfma_f32_16x16x32_bf16(av[m], bv[0], acc[m][0], 0, 0, 0);
            acc[m][1] = __builtin_amdgcn_mfma_f32_16x16x32_bf16(av[m], bv[1], acc[m][1], 0, 0, 0);
        }
        __builtin_amdgcn_s_setprio(0);

        // ---- phase 1: ks0, n{2,3} (av reused); stage Bk0(t+1)
        bv[0] = *(const bf16x8*)(Scur + 1 * 16384 + boff[2]);
        bv[1] = *(const bf16x8*)(Scur + 1 * 16384 + boff[3]);
        gload16(sB + scol + soff0, ldsn + 1 * 16384);
        gload16(sB + scol + soff1, ldsn + 1 * 16384 + 8192);
        asm volatile("s_waitcnt vmcnt(4)" ::: "memory");
        __builtin_amdgcn_s_barrier();
        __builtin_amdgcn_s_setprio(1);
#pragma unroll
        for (int m = 0; m < 8; ++m) {
            acc[m][2] = __builtin_amdgcn_mfma_f32_16x16x32_bf16(av[m], bv[0], acc[m][2], 0, 0, 0);
            acc[m][3] = __builtin_amdgcn_mfma_f32_16x16x32_bf16(av[m], bv[1], acc[m][3], 0, 0, 0);
        }
        __builtin_amdgcn_s_setprio(0);

        // ---- phase 2: ks1, n{0,1}; stage Ak1(t+1)
#pragma unroll
        for (int m = 0; m < 8; ++m) av[m] = *(const bf16x8*)(Scur + 2 * 16384 + aoff[m]);
        bv[0] = *(const bf16x8*)(Scur + 3 * 16384 + boff[0]);
        bv[1] = *(const bf16x8*)(Scur + 3 * 16384 + boff[1]);
        gload16(sA + scol + 32 + soff0, ldsn + 2 * 16384);
        gload16(sA + scol + 32 + soff1, ldsn + 2 * 16384 + 8192);
        asm volatile("s_waitcnt vmcnt(6)" ::: "memory");
        __builtin_amdgcn_s_barrier();
        __builtin_amdgcn_s_setprio(1);
#pragma unroll
        for (int m = 0; m < 8; ++m) {
            acc[m][0] = __builtin_amdgcn_mfma_f32_16x16x32_bf16(av[m], bv[0], acc[m][0], 0, 0, 0);
            acc[m][1] = __builtin_amdgcn_mfma_f32_16x16x32_bf16(av[m], bv[1], acc[m][1], 0, 0, 0);
        }
        __builtin_amdgcn_s_setprio(0);

        // ---- phase 3: ks1, n{2,3}; stage Bk1(t+1)
        bv[0] = *(const bf16x8*)(Scur + 3 * 16384 + boff[2]);
        bv[1] = *(const bf16x8*)(Scur + 3 * 16384 + boff[3]);
        gload16(sB + scol + 32 + soff0, ldsn + 3 * 16384);
        gload16(sB + scol + 32 + soff1, ldsn + 3 * 16384 + 8192);
        asm volatile("s_waitcnt vmcnt(4)" ::: "memory");
        __builtin_amdgcn_s_barrier();
        __builtin_amdgcn_s_setprio(1);
#pragma unroll
        for (int m = 0; m < 8; ++m) {
            acc[m][2] = __builtin_amdgcn_mfma_f32_16x16x32_bf16(av[m], bv[0], acc[m][2], 0, 0, 0);
            acc[m][3] = __builtin_amdgcn_mfma_f32_16x16x32_bf16(av[m], bv[1], acc[m][3], 0, 0, 0);
        }
        __builtin_amdgcn_s_setprio(0);

        // advance staging decode (tile t+2); clamp at the end (dummy restage of
        // the last work's kt=0 -- in-bounds, never consumed)
        if (++s_kt == NKT) {
            s_kt = 0;
            if (s_W + 1 < W0 + WPB) {
                ++s_W;
                sA = Qn + (size_t)(s_W >> 8) * 256 * DK;
                sB = Bn + (size_t)(s_W & 255) * 256 * DK;
            }
        }
        // compute-side work end: fold acc -> running rowmax; flush on mt change / last
        if (++c_kt == NKT) {
            c_kt = 0;
#pragma unroll
            for (int m = 0; m < 8; ++m)
#pragma unroll
                for (int r = 0; r < 4; ++r) {
                    float v = fmaxf(fmaxf(acc[m][0][r], acc[m][1][r]),
                                    fmaxf(acc[m][2][r], acc[m][3][r]));
                    v = fmaxf(v, __shfl_xor(v, 1, 64));
                    v = fmaxf(v, __shfl_xor(v, 2, 64));
                    v = fmaxf(v, __shfl_xor(v, 4, 64));
                    v = fmaxf(v, __shfl_xor(v, 8, 64));
                    rm[m][r] = fmaxf(rm[m][r], v);
                    acc[m][0][r] = 0.f; acc[m][1][r] = 0.f;
                    acc[m][2][r] = 0.f; acc[m][3][r] = 0.f;
                }
            const int mt_d = c_W >> 8;
            const bool last = (c_W == W0 + WPB - 1);
            ++c_W;
            if (last || (c_W >> 8) != mt_d) {
                if (mn == 0) {
#pragma unroll
                    for (int m = 0; m < 8; ++m)
#pragma unroll
                        for (int r = 0; r < 4; ++r) {
                            int row = mt_d * 256 + wm * 128 + m * 16 + kb * 4 + r;
                            float d2 = fmaxf(2.0f - 2.0f * rm[m][r], 0.0f);
                            atomicMin(best + row, __float_as_uint(d2));
                        }
                }
#pragma unroll
                for (int m = 0; m < 8; ++m)
#pragma unroll
                    for (int r = 0; r < 4; ++r) rm[m][r] = -3.0e38f;
            }
        }
    }
    asm volatile("s_waitcnt vmcnt(0)" ::: "memory");  // drain dummy stages before endpgm
}

// One wave per batch: d = sqrt(d2), mean of top-20 of 196.
__global__ void topk_kernel(const unsigned* __restrict__ best, float* __restrict__ out) {
    const int b = blockIdx.x;
    const int l = threadIdx.x;  // 64 threads
    float v[4];
#pragma unroll
    for (int s = 0; s < 4; ++s) {
        int idx = s * 64 + l;
        v[s] = (idx < 196) ? sqrtf(__uint_as_float(best[b * 196 + idx])) : -1.0f;
    }
    float sum = 0.f;
    for (int it = 0; it < 20; ++it) {
        float m = v[0]; int slot = 0;
#pragma unroll
        for (int s = 1; s < 4; ++s) if (v[s] > m) { m = v[s]; slot = s; }
        float wm = m;
#pragma unroll
        for (int msk = 1; msk < 64; msk <<= 1) wm = fmaxf(wm, __shfl_xor(wm, msk, 64));
        sum += wm;
        unsigned long long owners = __ballot(m == wm);
        int first = __ffsll((unsigned long long)owners) - 1;
        if (l == first) v[slot] = -1.0f;
    }
    if (l == 0) out[b] = sum * (1.0f / 20.0f);
}

__global__ void fill_kernel(float* out, int n, float val) {
    int i = blockIdx.x * blockDim.x + threadIdx.x;
    if (i < n) out[i] = val;
}

extern "C" void kernel_launch(void* const* d_in, const int* in_sizes, int n_in,
                              void* d_out, int out_size, void* d_ws, size_t ws_size,
                              hipStream_t stream) {
    const float* patch = (const float*)d_in[0];
    const float* bank  = (const float*)d_in[1];
    float* out = (float*)d_out;

    const size_t bankBytes = (size_t)NM * DK * 2;       // 201.3 MB bf16
    const size_t qOff      = bankBytes;
    const size_t qBytes    = (size_t)NQP * DK * 2;      // 19.7 MB bf16 (padded rows)
    const size_t bestOff   = qOff + qBytes;
    const size_t need      = bestOff + (size_t)NQP * 4;

    if (ws_size < need) {  // visible sentinel: ws too small
        fill_kernel<<<1, 64, 0, stream>>>(out, out_size, 1.0e9f);
        return;
    }

    u16*      bankB = (u16*)((char*)d_ws);
    u16*      qB    = (u16*)((char*)d_ws + qOff);
    unsigned* best  = (unsigned*)((char*)d_ws + bestOff);

    hipFuncSetAttribute((const void*)gemm8_kernel,
                        hipFuncAttributeMaxDynamicSharedMemorySize, 131072);

    norm_rows_kernel<<<dim3(NM / 4), 256, 0, stream>>>(bank, bankB, NM);
    norm_rows_kernel<<<dim3(NQ / 4), 256, 0, stream>>>(patch, qB, NQ);
    hipMemsetAsync(best, 0x7F, (size_t)NQP * 4, stream);  // +big float, uint-ordered
    gemm8_kernel<<<dim3(256), 512, 131072, stream>>>(qB, bankB, best);
    topk_kernel<<<dim3(32), 64, 0, stream>>>(best, out);
}